// Round 2
// baseline (479.959 us; speedup 1.0000x reference)
//
#include <hip/hip_runtime.h>
#include <hip/hip_bf16.h>

#define NN      100000
#define DF      64
#define NPB     64          // nodes per block
#define CHUNK   256         // edges per chunk (4 waves x 4 groups x 16 edges)
#define NBLK    ((NN + NPB - 1) / NPB)   // 1563

typedef __bf16 bf16x8 __attribute__((ext_vector_type(8)));
typedef float  f32x4  __attribute__((ext_vector_type(4)));

// tanh-approx gelu written as x * sigmoid(2u), u = 0.79788456*(x + 0.044715 x^3)
__device__ __forceinline__ float gelu_f(float x) {
    float u2 = x * (1.5957691216057308f + 0.07135481627f * x * x);
    float s  = __expf(-u2);
    return __fdividef(x, 1.0f + s);
}

__global__ __launch_bounds__(256, 4)
void it_fused(const float* __restrict__ y, const float* __restrict__ fy,
              const float* __restrict__ W0, const float* __restrict__ b0,
              const float* __restrict__ W1, const float* __restrict__ b1,
              const int* __restrict__ nbr, const int* __restrict__ splits,
              float* __restrict__ out)
{
    __shared__ int   splitsL[NPB + 1];
    __shared__ float yselfL[NPB][3];
    __shared__ float nodeacc[NPB][DF];
    __shared__ float aggL[CHUNK][6];
    __shared__ int   nbrL[CHUNK];
    __shared__ int   segL[CHUNK];

    const int t    = threadIdx.x;
    const int n0   = blockIdx.x * NPB;
    const int nloc = min(NPB, NN - n0);

    if (t <= NPB) splitsL[t] = splits[min(n0 + t, NN)];
    if (t < NPB) {
        const int node = min(n0 + t, NN - 1);
        yselfL[t][0] = y[node * 3 + 0];
        yselfL[t][1] = y[node * 3 + 1];
        yselfL[t][2] = y[node * 3 + 2];
    }
    for (int i = t; i < NPB * DF; i += 256) ((float*)nodeacc)[i] = 0.0f;
    __syncthreads();

    const int e_begin = splitsL[0];
    const int e_end   = splitsL[NPB];

    const int lane = t & 63;
    const int wv   = t >> 6;
    const int col  = lane & 15;   // MFMA N-index / A-row index
    const int kg   = lane >> 4;   // MFMA K-group

    // prefetch chunk 0's neighbor index (one edge per thread)
    int nb_next = ((e_begin + t) < e_end) ? nbr[e_begin + t] : 0;

    // ---- hoisted constants (per-lane slices; L1-served reloads are fine) ----
    float w0r[2][8][6];
    float b0r[2][8];
    #pragma unroll
    for (int kf = 0; kf < 2; kf++)
        #pragma unroll
        for (int j = 0; j < 8; j++) {
            const int c = kf * 32 + kg * 8 + j;
            #pragma unroll
            for (int k = 0; k < 6; k++) w0r[kf][j][k] = W0[k * DF + c];
            b0r[kf][j] = b0[c];
        }
    float  b1r[4];
    bf16x8 bfrag[4][2];   // W1 B-fragments: B[k=(kf*32+kg*8+j)][n=nt*16+col]
    #pragma unroll
    for (int nt = 0; nt < 4; nt++) {
        b1r[nt] = b1[nt * 16 + col];
        #pragma unroll
        for (int kf = 0; kf < 2; kf++)
            #pragma unroll
            for (int j = 0; j < 8; j++)
                bfrag[nt][kf][j] = (__bf16)W1[(kf * 32 + kg * 8 + j) * DF + nt * 16 + col];
    }

    const int nchunks = (e_end - e_begin + CHUNK - 1) / CHUNK;

    for (int chk = 0; chk < nchunks; chk++) {
        const int ebase = e_begin + chk * CHUNK;
        const int e     = ebase + t;
        const int nb    = nb_next;

        // segment id via binary search over 64 intervals (6 LDS broadcast reads)
        int sg = 0;
        #pragma unroll
        for (int step = 32; step >= 1; step >>= 1)
            if (splitsL[sg + step] <= e) sg += step;
        sg = min(sg, NPB - 1);

        float a0 = 0.f, a1 = 0.f, a2 = 0.f;
        if (e < e_end) {
            a0 = y[nb * 3 + 0]; a1 = y[nb * 3 + 1]; a2 = y[nb * 3 + 2];
        }
        // prefetch next chunk's neighbor index (latency hides under compute)
        const int en = e + CHUNK;
        nb_next = (en < e_end) ? nbr[en] : 0;

        aggL[t][0] = a0; aggL[t][1] = a1; aggL[t][2] = a2;
        aggL[t][3] = yselfL[sg][0]; aggL[t][4] = yselfL[sg][1]; aggL[t][5] = yselfL[sg][2];
        nbrL[t] = nb; segL[t] = sg;
        __syncthreads();

        // ---- each wave: 4 groups of 16 edges ----
        #pragma unroll
        for (int g = 0; g < 4; g++) {
            const int gbase = wv * 64 + g * 16;
            const int erow  = gbase + col;     // this lane's A-row edge (within chunk)
            const float g0 = aggL[erow][0], g1 = aggL[erow][1], g2 = aggL[erow][2],
                        g3 = aggL[erow][3], g4 = aggL[erow][4], g5 = aggL[erow][5];

            // Phase B: h0 = gelu(agg@W0+b0), built directly in A-fragment layout
            bf16x8 af[2];
            #pragma unroll
            for (int kf = 0; kf < 2; kf++)
                #pragma unroll
                for (int j = 0; j < 8; j++) {
                    float h = b0r[kf][j];
                    h += g0 * w0r[kf][j][0]; h += g1 * w0r[kf][j][1];
                    h += g2 * w0r[kf][j][2]; h += g3 * w0r[kf][j][3];
                    h += g4 * w0r[kf][j][4]; h += g5 * w0r[kf][j][5];
                    af[kf][j] = (__bf16)gelu_f(h);
                }

            // Phase C: h1 = h0 @ W1 (fp32 accum)
            f32x4 acc[4] = {};
            #pragma unroll
            for (int nt = 0; nt < 4; nt++) {
                acc[nt] = __builtin_amdgcn_mfma_f32_16x16x32_bf16(af[0], bfrag[nt][0], acc[nt], 0, 0, 0);
                acc[nt] = __builtin_amdgcn_mfma_f32_16x16x32_bf16(af[1], bfrag[nt][1], acc[nt], 0, 0, 0);
            }

            // Phase D: gate by f_y[nbr], segmented-reduce into LDS node accumulators
            const int equad = gbase + kg * 4;          // first edge of this lane's D-row quad
            const int s0 = segL[equad + 0], s1 = segL[equad + 1],
                      s2 = segL[equad + 2], s3 = segL[equad + 3];
            const int nb0 = nbrL[equad + 0], nb1 = nbrL[equad + 1],
                      nb2 = nbrL[equad + 2], nb3 = nbrL[equad + 3];
            const int rem = e_end - (ebase + equad);   // reg r valid iff r < rem
            #pragma unroll
            for (int nt = 0; nt < 4; nt++) {
                const int   c  = nt * 16 + col;
                const float bb = b1r[nt];
                float v0 = (0 < rem) ? (acc[nt][0] + bb) * fy[nb0 * DF + c] : 0.0f;
                float v1 = (1 < rem) ? (acc[nt][1] + bb) * fy[nb1 * DF + c] : 0.0f;
                float v2 = (2 < rem) ? (acc[nt][2] + bb) * fy[nb2 * DF + c] : 0.0f;
                float v3 = (3 < rem) ? (acc[nt][3] + bb) * fy[nb3 * DF + c] : 0.0f;
                if (s0 == s3) {   // monotone -> all four equal: merged single LDS atomic
                    unsafeAtomicAdd(&nodeacc[s0][c], ((v0 + v1) + (v2 + v3)));
                } else {
                    unsafeAtomicAdd(&nodeacc[s0][c], v0);
                    unsafeAtomicAdd(&nodeacc[s1][c], v1);
                    unsafeAtomicAdd(&nodeacc[s2][c], v2);
                    unsafeAtomicAdd(&nodeacc[s3][c], v3);
                }
            }
        }
        __syncthreads();   // protects aggL/nbrL/segL reuse + orders LDS atomics
    }

    // ---- Epilogue: mean and store (each node owned by exactly this block) ----
    for (int i = t; i < nloc * DF; i += 256) {
        const int node = i >> 6;
        const int cnt  = splitsL[node + 1] - splitsL[node];
        const float inv = (cnt > 0) ? __fdividef(1.0f, (float)cnt) : 0.0f;
        out[n0 * DF + i] = ((float*)nodeacc)[i] * inv;
    }
}

extern "C" void kernel_launch(void* const* d_in, const int* in_sizes, int n_in,
                              void* d_out, int out_size, void* d_ws, size_t ws_size,
                              hipStream_t stream) {
    const float* y   = (const float*)d_in[0];
    const float* fyv = (const float*)d_in[1];
    const float* W0  = (const float*)d_in[2];
    const float* b0  = (const float*)d_in[3];
    const float* W1  = (const float*)d_in[4];
    const float* b1  = (const float*)d_in[5];
    const int*   nb  = (const int*)d_in[6];   // harness delivers integer inputs as int32
    const int*   sp  = (const int*)d_in[7];
    it_fused<<<NBLK, 256, 0, stream>>>(y, fyv, W0, b0, W1, b1, nb, sp, (float*)d_out);
}

// Round 3
// 329.474 us; speedup vs baseline: 1.4567x; 1.4567x over previous
//
#include <hip/hip_runtime.h>
#include <hip/hip_bf16.h>

#define NN    100000
#define DF    64
#define NPB   64
#define NBLK  ((NN + NPB - 1) / NPB)   // 1563

typedef __bf16 bf16x8 __attribute__((ext_vector_type(8)));
typedef float  f32x4  __attribute__((ext_vector_type(4)));

// tanh-approx gelu: x * sigmoid(2u), u = 0.79788456*(x + 0.044715 x^3)
__device__ __forceinline__ float gelu_f(float x) {
    float u2 = x * (1.5957691216057308f + 0.07135481627f * x * x);
    float s  = __expf(-u2);
    return __fdividef(x, 1.0f + s);
}

__global__ __launch_bounds__(256, 3)
void it_fused(const float* __restrict__ y, const float* __restrict__ fy,
              const float* __restrict__ W0, const float* __restrict__ b0,
              const float* __restrict__ W1, const float* __restrict__ b1,
              const int* __restrict__ nbr, const int* __restrict__ splits,
              float* __restrict__ out)
{
    __shared__ int   splitsL[NPB + 1];
    __shared__ float yselfL[NPB][3];
    __shared__ float nodeacc[NPB][DF];
    __shared__ int2  nsL[4][16];                         // per-wave (nbr, seg)
    __shared__ __align__(16) __bf16 hL[4][16][DF];       // per-wave h0 transpose buf (swizzled)

    const int t    = threadIdx.x;
    const int n0   = blockIdx.x * NPB;
    const int nloc = min(NPB, NN - n0);

    if (t <= NPB) splitsL[t] = splits[min(n0 + t, NN)];
    if (t < NPB) {
        const int node = min(n0 + t, NN - 1);
        yselfL[t][0] = y[node * 3 + 0];
        yselfL[t][1] = y[node * 3 + 1];
        yselfL[t][2] = y[node * 3 + 2];
    }
    for (int i = t; i < NPB * DF; i += 256) ((float*)nodeacc)[i] = 0.0f;
    __syncthreads();

    const int e_begin = splitsL[0];
    const int e_end   = splitsL[NPB];
    const int lane = t & 63;
    const int wv   = t >> 6;
    const int col  = lane & 15;   // MFMA m/n minor index
    const int kg   = lane >> 4;   // MFMA K-group

    // ---- weight B-fragments (small, register-resident) ----
    bf16x8 w0f[4];                // B[k=kg*8+j][n=nt*16+col], K padded 6->32 with zeros
    #pragma unroll
    for (int nt = 0; nt < 4; nt++)
        #pragma unroll
        for (int j = 0; j < 8; j++) {
            const int k = kg * 8 + j;
            const float v = W0[min(k, 5) * DF + nt * 16 + col];  // clamped addr, masked below
            w0f[nt][j] = (k < 6) ? (__bf16)v : (__bf16)0.0f;
        }
    bf16x8 w1f[4][2];             // B[k=kf*32+kg*8+j][n=nt*16+col]
    float  b0r[4], b1r[4];
    #pragma unroll
    for (int nt = 0; nt < 4; nt++) {
        b0r[nt] = b0[nt * 16 + col];
        b1r[nt] = b1[nt * 16 + col];
        #pragma unroll
        for (int kf = 0; kf < 2; kf++)
            #pragma unroll
            for (int j = 0; j < 8; j++)
                w1f[nt][kf][j] = (__bf16)W1[(kf * 32 + kg * 8 + j) * DF + nt * 16 + col];
    }

    __bf16* const hw = &hL[wv][0][0];

    // ---- barrier-free edge loop: each wave owns independent 16-edge batches ----
    for (int eb = e_begin + wv * 16; eb < e_end; eb += 64) {
        // per-edge prep by kg==0 lanes (one edge per lane)
        bf16x8 af0 = {};
        if (kg == 0) {
            const int e = eb + col;
            int nb = 0, sg = 0;
            float a0 = 0.f, a1 = 0.f, a2 = 0.f;
            if (e < e_end) {
                nb = nbr[e];
                #pragma unroll
                for (int step = 32; step >= 1; step >>= 1)
                    if (splitsL[sg + step] <= e) sg += step;
                a0 = y[nb * 3 + 0]; a1 = y[nb * 3 + 1]; a2 = y[nb * 3 + 2];
            }
            nsL[wv][col] = make_int2(nb, sg);
            af0[0] = (__bf16)a0; af0[1] = (__bf16)a1; af0[2] = (__bf16)a2;
            af0[3] = (__bf16)yselfL[sg][0];
            af0[4] = (__bf16)yselfL[sg][1];
            af0[5] = (__bf16)yselfL[sg][2];
        }

        // layer 0: hpre = agg @ W0   (K=32, only k<6 nonzero)
        f32x4 acc0[4] = {};
        #pragma unroll
        for (int nt = 0; nt < 4; nt++)
            acc0[nt] = __builtin_amdgcn_mfma_f32_16x16x32_bf16(af0, w0f[nt], acc0[nt], 0, 0, 0);

        // gelu + transpose to A-layout via per-wave swizzled LDS (within-wave lgkmcnt only)
        #pragma unroll
        for (int nt = 0; nt < 4; nt++)
            #pragma unroll
            for (int r = 0; r < 4; r++) {
                const int row = kg * 4 + r;
                const float h = gelu_f(acc0[nt][r] + b0r[nt]);
                const int byteoff = row * 128 + ((((nt * 16 + col) * 2)) ^ ((row & 7) << 4));
                *(__bf16*)((char*)hw + byteoff) = (__bf16)h;
            }
        bf16x8 af1[2];
        #pragma unroll
        for (int kf = 0; kf < 2; kf++) {
            const int byteoff = col * 128 + ((kf * 64 + kg * 16) ^ ((col & 7) << 4));
            af1[kf] = *(const bf16x8*)((const char*)hw + byteoff);
        }

        // layer 1: h1 = h0 @ W1  (fp32 accum)
        f32x4 acc[4] = {};
        #pragma unroll
        for (int nt = 0; nt < 4; nt++) {
            acc[nt] = __builtin_amdgcn_mfma_f32_16x16x32_bf16(af1[0], w1f[nt][0], acc[nt], 0, 0, 0);
            acc[nt] = __builtin_amdgcn_mfma_f32_16x16x32_bf16(af1[1], w1f[nt][1], acc[nt], 0, 0, 0);
        }

        // gate by f_y[nbr], segmented-reduce into LDS node accumulators
        const int2 q0 = nsL[wv][kg * 4 + 0];
        const int2 q1 = nsL[wv][kg * 4 + 1];
        const int2 q2 = nsL[wv][kg * 4 + 2];
        const int2 q3 = nsL[wv][kg * 4 + 3];
        const int rem = e_end - (eb + kg * 4);
        #pragma unroll
        for (int nt = 0; nt < 4; nt++) {
            const int   c  = nt * 16 + col;
            const float bb = b1r[nt];
            float v0 = (0 < rem) ? (acc[nt][0] + bb) * fy[q0.x * DF + c] : 0.0f;
            float v1 = (1 < rem) ? (acc[nt][1] + bb) * fy[q1.x * DF + c] : 0.0f;
            float v2 = (2 < rem) ? (acc[nt][2] + bb) * fy[q2.x * DF + c] : 0.0f;
            float v3 = (3 < rem) ? (acc[nt][3] + bb) * fy[q3.x * DF + c] : 0.0f;
            if (q0.y == q3.y) {   // monotone seg -> all four equal: merged single atomic
                unsafeAtomicAdd(&nodeacc[q0.y][c], ((v0 + v1) + (v2 + v3)));
            } else {
                unsafeAtomicAdd(&nodeacc[q0.y][c], v0);
                unsafeAtomicAdd(&nodeacc[q1.y][c], v1);
                unsafeAtomicAdd(&nodeacc[q2.y][c], v2);
                unsafeAtomicAdd(&nodeacc[q3.y][c], v3);
            }
        }
    }

    __syncthreads();

    // ---- Epilogue: mean and store (each node owned by exactly this block) ----
    for (int i = t; i < nloc * DF; i += 256) {
        const int node = i >> 6;
        const int cnt  = splitsL[node + 1] - splitsL[node];
        const float inv = (cnt > 0) ? __fdividef(1.0f, (float)cnt) : 0.0f;
        out[n0 * DF + i] = ((float*)nodeacc)[i] * inv;
    }
}

extern "C" void kernel_launch(void* const* d_in, const int* in_sizes, int n_in,
                              void* d_out, int out_size, void* d_ws, size_t ws_size,
                              hipStream_t stream) {
    const float* y   = (const float*)d_in[0];
    const float* fyv = (const float*)d_in[1];
    const float* W0  = (const float*)d_in[2];
    const float* b0  = (const float*)d_in[3];
    const float* W1  = (const float*)d_in[4];
    const float* b1  = (const float*)d_in[5];
    const int*   nb  = (const int*)d_in[6];   // harness delivers integer inputs as int32
    const int*   sp  = (const int*)d_in[7];
    it_fused<<<NBLK, 256, 0, stream>>>(y, fyv, W0, b0, W1, b1, nb, sp, (float*)d_out);
}

// Round 4
// 319.882 us; speedup vs baseline: 1.5004x; 1.0300x over previous
//
#include <hip/hip_runtime.h>
#include <hip/hip_bf16.h>

#define NN    100000
#define DF    64
#define NPB   64
#define NBLK  ((NN + NPB - 1) / NPB)   // 1563

typedef __bf16 bf16x8 __attribute__((ext_vector_type(8)));
typedef float  f32x4  __attribute__((ext_vector_type(4)));

// tanh-approx gelu: x * sigmoid(2u), u = 0.79788456*(x + 0.044715 x^3)
__device__ __forceinline__ float gelu_f(float x) {
    float u2 = x * (1.5957691216057308f + 0.07135481627f * x * x);
    float s  = __expf(-u2);
    return __fdividef(x, 1.0f + s);
}

__global__ __launch_bounds__(256, 4)
void it_fused(const float* __restrict__ y, const float* __restrict__ fy,
              const float* __restrict__ W0, const float* __restrict__ b0,
              const float* __restrict__ W1, const float* __restrict__ b1,
              const int* __restrict__ nbr, const int* __restrict__ splits,
              float* __restrict__ out)
{
    __shared__ int   splitsL[NPB + 1];
    __shared__ float yselfL[NPB][3];
    __shared__ float nodeacc[NPB][DF];
    __shared__ int2  nsL[4][64];                          // per-wave (nbr, seg), one per edge
    __shared__ __align__(16) __bf16 aggW[4][64][8];       // per-wave agg rows (K padded 6->8)
    __shared__ __align__(16) __bf16 hL[4][2][16][DF];     // per-wave, per-group-parity transpose buf

    const int t    = threadIdx.x;
    const int n0   = blockIdx.x * NPB;
    const int nloc = min(NPB, NN - n0);

    if (t <= NPB) splitsL[t] = splits[min(n0 + t, NN)];
    if (t < NPB) {
        const int node = min(n0 + t, NN - 1);
        yselfL[t][0] = y[node * 3 + 0];
        yselfL[t][1] = y[node * 3 + 1];
        yselfL[t][2] = y[node * 3 + 2];
    }
    for (int i = t; i < NPB * DF / 4; i += 256) ((float4*)nodeacc)[i] = make_float4(0, 0, 0, 0);
    __syncthreads();

    const int e_begin = splitsL[0];
    const int e_end   = splitsL[NPB];
    const int lane = t & 63;
    const int wv   = t >> 6;
    const int col  = lane & 15;   // MFMA m/n minor index
    const int kg   = lane >> 4;   // MFMA K-group

    // ---- weight B-fragments (register-resident) ----
    bf16x8 w0f[4];                // B[k=kg*8+j][n=nt*16+col], K padded 6->32 with zeros
    #pragma unroll
    for (int nt = 0; nt < 4; nt++)
        #pragma unroll
        for (int j = 0; j < 8; j++) {
            const int k = kg * 8 + j;
            const float v = W0[min(k, 5) * DF + nt * 16 + col];
            w0f[nt][j] = (k < 6) ? (__bf16)v : (__bf16)0.0f;
        }
    bf16x8 w1f[4][2];             // B[k=kf*32+kg*8+j][n=nt*16+col]
    float  b0r[4], b1r[4];
    #pragma unroll
    for (int nt = 0; nt < 4; nt++) {
        b0r[nt] = b0[nt * 16 + col];
        b1r[nt] = b1[nt * 16 + col];
        #pragma unroll
        for (int kf = 0; kf < 2; kf++)
            #pragma unroll
            for (int j = 0; j < 8; j++)
                w1f[nt][kf][j] = (__bf16)W1[(kf * 32 + kg * 8 + j) * DF + nt * 16 + col];
    }

    // ---- pipeline prologue: cold-load first batch's (nbr, y) ----
    const int efirst = e_begin + wv * 64 + lane;
    int   nb_cur = 0;
    float ya0 = 0.f, ya1 = 0.f, ya2 = 0.f;
    if (efirst < e_end) {
        nb_cur = nbr[efirst];
        ya0 = y[nb_cur * 3 + 0]; ya1 = y[nb_cur * 3 + 1]; ya2 = y[nb_cur * 3 + 2];
    }

    // ---- barrier-free main loop: each wave owns 64-edge batches, stride 256 ----
    for (int ebase = e_begin + wv * 64; ebase < e_end; ebase += 256) {
        const int e = ebase + lane;

        int sg = 0;
        #pragma unroll
        for (int step = 32; step >= 1; step >>= 1)
            if (splitsL[sg + step] <= e) sg += step;
        sg = min(sg, NPB - 1);

        nsL[wv][lane] = make_int2(nb_cur, sg);
        bf16x8 ag = {};
        ag[0] = (__bf16)ya0; ag[1] = (__bf16)ya1; ag[2] = (__bf16)ya2;
        ag[3] = (__bf16)yselfL[sg][0];
        ag[4] = (__bf16)yselfL[sg][1];
        ag[5] = (__bf16)yselfL[sg][2];
        *(bf16x8*)&aggW[wv][lane][0] = ag;

        // prefetch next batch's neighbor index (hides under groups 0-1)
        const int en = e + 256;
        int nb_nxt = 0;
        if (en < e_end) nb_nxt = nbr[en];

        auto group = [&](int g) {
            const int gb = g * 16;
            const int qi = gb + kg * 4;
            const int2 q0 = nsL[wv][qi + 0], q1 = nsL[wv][qi + 1],
                       q2 = nsL[wv][qi + 2], q3 = nsL[wv][qi + 3];

            bf16x8 af0 = {};
            if (kg == 0) af0 = *(const bf16x8*)&aggW[wv][gb + col][0];

            // layer 0 (K=32, only k<6 nonzero)
            f32x4 acc0[4] = {};
            #pragma unroll
            for (int nt = 0; nt < 4; nt++)
                acc0[nt] = __builtin_amdgcn_mfma_f32_16x16x32_bf16(af0, w0f[nt], acc0[nt], 0, 0, 0);

            // gelu + bias, transpose edge<->feature via swizzled per-wave LDS
            __bf16* const hw = &hL[wv][g & 1][0][0];
            #pragma unroll
            for (int nt = 0; nt < 4; nt++)
                #pragma unroll
                for (int r = 0; r < 4; r++) {
                    const int row = kg * 4 + r;
                    const float h = gelu_f(acc0[nt][r] + b0r[nt]);
                    const int byteoff = row * 128 + ((((nt * 16 + col) * 2)) ^ ((row & 7) << 4));
                    *(__bf16*)((char*)hw + byteoff) = (__bf16)h;
                }
            bf16x8 af1[2];
            #pragma unroll
            for (int kf = 0; kf < 2; kf++) {
                const int byteoff = col * 128 + ((kf * 64 + kg * 16) ^ ((col & 7) << 4));
                af1[kf] = *(const bf16x8*)((const char*)hw + byteoff);
            }

            // layer 1 (fp32 accum)
            f32x4 acc[4] = {};
            #pragma unroll
            for (int nt = 0; nt < 4; nt++) {
                acc[nt] = __builtin_amdgcn_mfma_f32_16x16x32_bf16(af1[0], w1f[nt][0], acc[nt], 0, 0, 0);
                acc[nt] = __builtin_amdgcn_mfma_f32_16x16x32_bf16(af1[1], w1f[nt][1], acc[nt], 0, 0, 0);
            }

            // gate by f_y[nbr], segmented-reduce into LDS node accumulators
            const float* f0 = fy + q0.x * DF;
            const float* f1 = fy + q1.x * DF;
            const float* f2 = fy + q2.x * DF;
            const float* f3 = fy + q3.x * DF;
            const int rem = e_end - (ebase + qi);
            #pragma unroll
            for (int nt = 0; nt < 4; nt++) {
                const int   c  = nt * 16 + col;
                const float bb = b1r[nt];
                float v0 = (0 < rem) ? (acc[nt][0] + bb) * f0[c] : 0.0f;
                float v1 = (1 < rem) ? (acc[nt][1] + bb) * f1[c] : 0.0f;
                float v2 = (2 < rem) ? (acc[nt][2] + bb) * f2[c] : 0.0f;
                float v3 = (3 < rem) ? (acc[nt][3] + bb) * f3[c] : 0.0f;
                if (q0.y == q3.y) {   // monotone seg -> all four equal: merged single atomic
                    unsafeAtomicAdd(&nodeacc[q0.y][c], ((v0 + v1) + (v2 + v3)));
                } else {
                    unsafeAtomicAdd(&nodeacc[q0.y][c], v0);
                    unsafeAtomicAdd(&nodeacc[q1.y][c], v1);
                    unsafeAtomicAdd(&nodeacc[q2.y][c], v2);
                    unsafeAtomicAdd(&nodeacc[q3.y][c], v3);
                }
            }
        };

        group(0); group(1);

        // mid-iter: gather next batch's y (nb_nxt landed under groups 0-1;
        // this gather's latency hides under groups 2-3)
        ya0 = ya1 = ya2 = 0.f;
        if (en < e_end) {
            ya0 = y[nb_nxt * 3 + 0]; ya1 = y[nb_nxt * 3 + 1]; ya2 = y[nb_nxt * 3 + 2];
        }
        nb_cur = nb_nxt;

        group(2); group(3);
    }

    __syncthreads();

    // ---- Epilogue: mean and store (each node owned by exactly this block) ----
    for (int i = t; i < nloc * (DF / 4); i += 256) {
        const int node = i >> 4;
        const int cnt  = splitsL[node + 1] - splitsL[node];
        const float inv = (cnt > 0) ? __fdividef(1.0f, (float)cnt) : 0.0f;
        float4 v = ((const float4*)nodeacc)[i];
        v.x *= inv; v.y *= inv; v.z *= inv; v.w *= inv;
        ((float4*)out)[n0 * (DF / 4) + i] = v;
    }
}

extern "C" void kernel_launch(void* const* d_in, const int* in_sizes, int n_in,
                              void* d_out, int out_size, void* d_ws, size_t ws_size,
                              hipStream_t stream) {
    const float* y   = (const float*)d_in[0];
    const float* fyv = (const float*)d_in[1];
    const float* W0  = (const float*)d_in[2];
    const float* b0  = (const float*)d_in[3];
    const float* W1  = (const float*)d_in[4];
    const float* b1  = (const float*)d_in[5];
    const int*   nb  = (const int*)d_in[6];   // harness delivers integer inputs as int32
    const int*   sp  = (const int*)d_in[7];
    it_fused<<<NBLK, 256, 0, stream>>>(y, fyv, W0, b0, W1, b1, nb, sp, (float*)d_out);
}